// Round 3
// baseline (524.749 us; speedup 1.0000x reference)
//
#include <hip/hip_runtime.h>

#define NN 50000
#define NE 400000
#define SCAN_NB 196   // ceil(50000/256)

__global__ void k_hist(const int* __restrict__ rcv, int* __restrict__ cnt){
  int e = blockIdx.x*256 + threadIdx.x;
  if (e < NE) atomicAdd(&cnt[rcv[e]], 1);
}

__global__ void k_scanA(const int* __restrict__ cnt, int* __restrict__ bsum){
  __shared__ int sh[256];
  int i = blockIdx.x*256 + threadIdx.x;
  int v = (i < NN) ? cnt[i] : 0;
  sh[threadIdx.x] = v; __syncthreads();
  for (int off=128; off>0; off>>=1){
    if (threadIdx.x < off) sh[threadIdx.x] += sh[threadIdx.x+off];
    __syncthreads();
  }
  if (threadIdx.x==0) bsum[blockIdx.x] = sh[0];
}

__global__ void k_scanB(int* __restrict__ bsum){
  __shared__ int sh[256];
  int t = threadIdx.x;
  int v = (t < SCAN_NB) ? bsum[t] : 0;
  sh[t] = v; __syncthreads();
  for (int off=1; off<256; off<<=1){
    int x = (t>=off)? sh[t-off] : 0;
    __syncthreads();
    sh[t] += x;
    __syncthreads();
  }
  if (t < SCAN_NB) bsum[t] = sh[t] - v;   // exclusive
}

__global__ void k_scanC(const int* __restrict__ cnt, const int* __restrict__ bsum,
                        int* __restrict__ offs, int* __restrict__ cursor){
  __shared__ int sh[256];
  int t = threadIdx.x;
  int i = blockIdx.x*256 + t;
  int v = (i < NN) ? cnt[i] : 0;
  sh[t] = v; __syncthreads();
  for (int off=1; off<256; off<<=1){
    int x = (t>=off)? sh[t-off] : 0;
    __syncthreads();
    sh[t] += x;
    __syncthreads();
  }
  int excl = sh[t] - v + bsum[blockIdx.x];
  if (i < NN){ offs[i] = excl; cursor[i] = excl; }
}

__global__ void k_scatter(const int* __restrict__ rcv, const int* __restrict__ snd,
                          int* __restrict__ cursor, int* __restrict__ csr_snd){
  int e = blockIdx.x*256 + threadIdx.x;
  if (e < NE){
    int p = atomicAdd(&cursor[rcv[e]], 1);
    csr_snd[p] = snd[e];
  }
}

// Pack W0..W3 into float4 table: Wp[m*64+t] = {W0,W1,W2,W3}[m][t]
__global__ void k_prepW(const float* __restrict__ W0, const float* __restrict__ W1,
                        const float* __restrict__ W2, const float* __restrict__ W3,
                        float4* __restrict__ Wp){
  int i = blockIdx.x*256 + threadIdx.x;   // 0..2047
  if (i < 2048) Wp[i] = make_float4(W0[i], W1[i], W2[i], W3[i]);
}

// Aggregate A[n][m][k] = sum_edges feat[snd][m]*sh_k(edge). Wave-per-node,
// lane=(m=lane&31, k-half=lane>>5), acc in 8 VGPRs. LDS only for sh staging
// (16KB/block -> full occupancy). Sender ids live in a VGPR, inner loop
// pulls them via readlane (no LDS round-trip).
__global__ __launch_bounds__(256) void k_aggr(
    const float* __restrict__ pos, const float* __restrict__ feat,
    const int* __restrict__ offs, const int* __restrict__ cnt,
    const int* __restrict__ csr_snd, float4* __restrict__ A4)
{
  __shared__ __align__(16) float smS[4][64][16];   // 16 KB

  const int tid = threadIdx.x, wv = tid>>6, lane = tid&63;
  const int ml = lane&31, hh = lane>>5;
  const int n = blockIdx.x*4 + wv;          // 12500*4 == 50000
  const float pnx=pos[n*3], pny=pos[n*3+1], pnz=pos[n*3+2];
  const int start = offs[n], deg = cnt[n];
  const int nch = (deg+63)>>6;

  float acc[8];
  #pragma unroll
  for (int j=0;j<8;++j) acc[j]=0.f;

  const float SC3=1.7320508f, SC5=2.236068f, SC7=2.6457513f, SC15=3.8729833f,
              SC42=6.4807407f, SC70=8.3666003f, SC105=10.246951f;

  for (int c=0; c<nch; ++c){
    const int base = c<<6;
    int cn = deg - base; cn = (cn>64)?64:cn;     // >=1 inside loop
    int sE = 0;
    if (lane < cn){
      sE = csr_snd[start+base+lane];
      float rx = pnx - pos[sE*3];
      float ry = pny - pos[sE*3+1];
      float rz = pnz - pos[sE*3+2];
      float r = sqrtf(rx*rx+ry*ry+rz*rz);
      float inv = 1.0f/fmaxf(r,1e-12f);
      float x=rx*inv, y=ry*inv, z=rz*inv;
      float x2=x*x, y2=y*y, z2=z*z;
      float s1=SC3*x, s2=SC3*y, s3=SC3*z;
      float s4=SC15*x*y, s5=SC15*y*z, s6=0.5f*SC5*(3.f*z2-1.f), s7=SC15*x*z;
      float s8=0.5f*SC15*(x2-y2);
      float s9 =0.25f*SC70*y*(3.f*x2-y2);
      float s10=SC105*x*y*z;
      float s11=0.25f*SC42*y*(5.f*z2-1.f);
      float s12=0.5f*SC7*z*(5.f*z2-3.f);
      float s13=0.25f*SC42*x*(5.f*z2-1.f);
      float s14=0.5f*SC105*z*(x2-y2);
      float s15=0.25f*SC70*x*(x2-3.f*y2);
      float4* wp = (float4*)&smS[wv][lane][0];
      wp[0] = make_float4(1.0f,s1,s2,s3);
      wp[1] = make_float4(s4,s5,s6,s7);
      wp[2] = make_float4(s8,s9,s10,s11);
      wp[3] = make_float4(s12,s13,s14,s15);
    }
    // same-wave LDS producer->consumer ordering (waves independent)
    asm volatile("s_waitcnt lgkmcnt(0)" ::: "memory");
    #pragma unroll 8
    for (int it=0; it<cn; ++it){
      int s = __builtin_amdgcn_readlane(sE, it);   // uniform sender id
      float f = feat[(size_t)s*32 + ml];           // 128B segment, L2-hot
      const float4* rp = (const float4*)&smS[wv][it][hh*8];
      float4 q0=rp[0], q1=rp[1];                   // broadcast reads
      acc[0]+=f*q0.x; acc[1]+=f*q0.y; acc[2]+=f*q0.z; acc[3]+=f*q0.w;
      acc[4]+=f*q1.x; acc[5]+=f*q1.y; acc[6]+=f*q1.z; acc[7]+=f*q1.w;
    }
    asm volatile("" ::: "memory");  // reads before next chunk's overwrites
  }

  // A[n][m][k]: lane (ml,hh) owns floats m=ml, k=hh*8..hh*8+7
  float4* dst = A4 + (size_t)n*128 + ml*4 + hh*2;
  dst[0] = make_float4(acc[0],acc[1],acc[2],acc[3]);
  dst[1] = make_float4(acc[4],acc[5],acc[6],acc[7]);
}

// Transform: out[n][t,k] = sum_m A[n][m][k]*W_{l(k)}[m][t] (+ self term).
// Wave-per-node, lane=t. A: coalesced global load -> per-wave LDS ->
// broadcast reads. W: packed float4 from global (32KB, L1-resident).
__global__ __launch_bounds__(256) void k_xform(
    const float* __restrict__ feat, const float4* __restrict__ A4,
    const float4* __restrict__ Wp, const float* __restrict__ Wsc,
    float* __restrict__ out)
{
  __shared__ __align__(16) float4 smA[4][128];    // 8 KB

  const int tid = threadIdx.x, wv = tid>>6, lane = tid&63;
  const int n = blockIdx.x*4 + wv;          // 12500*4 == 50000

  const float4* Ap = A4 + (size_t)n*128;
  smA[wv][lane]    = Ap[lane];              // coalesced 1KB
  smA[wv][lane+64] = Ap[lane+64];
  // compiler waits vmcnt before ds_write (data dep); order writes->reads:
  asm volatile("s_waitcnt lgkmcnt(0)" ::: "memory");

  float4 F[8];                               // self features (wave-uniform)
  const float4* f4 = (const float4*)(feat + (size_t)n*32);
  #pragma unroll
  for (int g=0; g<8; ++g) F[g] = f4[g];

  float oa[16];
  #pragma unroll
  for (int k=0;k<16;++k) oa[k]=0.f;
  float osc = 0.f;

  #pragma unroll 4
  for (int m=0; m<32; ++m){
    float4 wq = Wp[m*64 + lane];            // {W0,W1,W2,W3}[m][lane], L1
    float  w4 = Wsc[m*64 + lane];
    float4 a0 = smA[wv][m*4+0];             // A[m][0..3]   broadcast
    float4 a1 = smA[wv][m*4+1];
    float4 a2 = smA[wv][m*4+2];
    float4 a3 = smA[wv][m*4+3];
    const float fsm = ((const float*)&F[m>>2])[m&3];
    oa[0] += a0.x*wq.x;
    oa[1] += a0.y*wq.y; oa[2] += a0.z*wq.y; oa[3] += a0.w*wq.y;
    oa[4] += a1.x*wq.z; oa[5] += a1.y*wq.z; oa[6] += a1.z*wq.z;
    oa[7] += a1.w*wq.z; oa[8] += a2.x*wq.z;
    oa[9] += a2.y*wq.w; oa[10]+= a2.z*wq.w; oa[11]+= a2.w*wq.w;
    oa[12]+= a3.x*wq.w; oa[13]+= a3.y*wq.w; oa[14]+= a3.z*wq.w; oa[15]+= a3.w*wq.w;
    osc += fsm*w4;
  }

  const float S = 0.17677669529663687f;   // 1/sqrt(32)
  const float S8 = S*0.125f;              // edge terms also carry /DENOM
  float* o = out + (size_t)n*1024;
  o[lane] = oa[0]*S8 + osc*S;
  #pragma unroll
  for (int i=0;i<3;++i) o[64  + lane*3 + i] = oa[1+i]*S8;
  #pragma unroll
  for (int i=0;i<5;++i) o[256 + lane*5 + i] = oa[4+i]*S8;
  #pragma unroll
  for (int i=0;i<7;++i) o[576 + lane*7 + i] = oa[9+i]*S8;
}

extern "C" void kernel_launch(void* const* d_in, const int* in_sizes, int n_in,
                              void* d_out, int out_size, void* d_ws, size_t ws_size,
                              hipStream_t stream) {
  const float* pos  = (const float*)d_in[0];
  const float* feat = (const float*)d_in[1];
  const float* W0   = (const float*)d_in[2];
  const float* W1   = (const float*)d_in[3];
  const float* W2   = (const float*)d_in[4];
  const float* W3   = (const float*)d_in[5];
  const float* Wsc  = (const float*)d_in[6];
  const int*  snd   = (const int*)d_in[7];
  const int*  rcv   = (const int*)d_in[8];
  float* out = (float*)d_out;

  int* ws      = (int*)d_ws;
  int* cnt     = ws;            // 50000
  int* offs    = ws + 50000;    // 50000
  int* cursor  = ws + 100000;   // 50000
  int* bsum    = ws + 150000;   // 256
  int* csr_snd = ws + 150272;   // 400000  (ints end at 550272; 16B aligned)
  float4* Wp   = (float4*)(ws + 550272);          // 2048 float4 = 32 KB
  float4* A4   = (float4*)(ws + 558464);          // 50000*128 float4 = 102.4 MB

  hipMemsetAsync(cnt, 0, NN*sizeof(int), stream);
  k_hist   <<<(NE+255)/256, 256, 0, stream>>>(rcv, cnt);
  k_scanA  <<<SCAN_NB, 256, 0, stream>>>(cnt, bsum);
  k_scanB  <<<1, 256, 0, stream>>>(bsum);
  k_scanC  <<<SCAN_NB, 256, 0, stream>>>(cnt, bsum, offs, cursor);
  k_scatter<<<(NE+255)/256, 256, 0, stream>>>(rcv, snd, cursor, csr_snd);
  k_prepW  <<<8, 256, 0, stream>>>(W0, W1, W2, W3, Wp);
  k_aggr   <<<12500, 256, 0, stream>>>(pos, feat, offs, cnt, csr_snd, A4);
  k_xform  <<<12500, 256, 0, stream>>>(feat, A4, Wp, Wsc, out);
}

// Round 4
// 396.309 us; speedup vs baseline: 1.3241x; 1.3241x over previous
//
#include <hip/hip_runtime.h>

#define NN 50000
#define NE 400000
#define SCAN_NB 196   // ceil(50000/256)

__global__ void k_hist(const int* __restrict__ rcv, int* __restrict__ cnt){
  int e = blockIdx.x*256 + threadIdx.x;
  if (e < NE) atomicAdd(&cnt[rcv[e]], 1);
}

__global__ void k_scanA(const int* __restrict__ cnt, int* __restrict__ bsum){
  __shared__ int sh[256];
  int i = blockIdx.x*256 + threadIdx.x;
  int v = (i < NN) ? cnt[i] : 0;
  sh[threadIdx.x] = v; __syncthreads();
  for (int off=128; off>0; off>>=1){
    if (threadIdx.x < off) sh[threadIdx.x] += sh[threadIdx.x+off];
    __syncthreads();
  }
  if (threadIdx.x==0) bsum[blockIdx.x] = sh[0];
}

__global__ void k_scanB(int* __restrict__ bsum){
  __shared__ int sh[256];
  int t = threadIdx.x;
  int v = (t < SCAN_NB) ? bsum[t] : 0;
  sh[t] = v; __syncthreads();
  for (int off=1; off<256; off<<=1){
    int x = (t>=off)? sh[t-off] : 0;
    __syncthreads();
    sh[t] += x;
    __syncthreads();
  }
  if (t < SCAN_NB) bsum[t] = sh[t] - v;   // exclusive
}

__global__ void k_scanC(const int* __restrict__ cnt, const int* __restrict__ bsum,
                        int* __restrict__ offs, int* __restrict__ cursor){
  __shared__ int sh[256];
  int t = threadIdx.x;
  int i = blockIdx.x*256 + t;
  int v = (i < NN) ? cnt[i] : 0;
  sh[t] = v; __syncthreads();
  for (int off=1; off<256; off<<=1){
    int x = (t>=off)? sh[t-off] : 0;
    __syncthreads();
    sh[t] += x;
    __syncthreads();
  }
  int excl = sh[t] - v + bsum[blockIdx.x];
  if (i < NN){ offs[i] = excl; cursor[i] = excl; }
}

__global__ void k_scatter(const int* __restrict__ rcv, const int* __restrict__ snd,
                          int* __restrict__ cursor, int* __restrict__ csr_snd){
  int e = blockIdx.x*256 + threadIdx.x;
  if (e < NE){
    int p = atomicAdd(&cursor[rcv[e]], 1);
    csr_snd[p] = snd[e];
  }
}

// Pack W0..W3 into float4 table: Wp[m*64+t] = {W0,W1,W2,W3}[m][t]
__global__ void k_prepW(const float* __restrict__ W0, const float* __restrict__ W1,
                        const float* __restrict__ W2, const float* __restrict__ W3,
                        float4* __restrict__ Wp){
  int i = blockIdx.x*256 + threadIdx.x;   // 0..2047
  if (i < 2048) Wp[i] = make_float4(W0[i], W1[i], W2[i], W3[i]);
}

// Fused wave-per-node kernel. Phases (all per-wave, NO block barriers):
//  1) edge loop: SH->LDS stage, acc[m][k] in regs (lane=(m=lane&31,k-half))
//  2) acc -> LDS as A[32][16] (reuses SH buffer)
//  3) transform: oa[t][k] = sum_m A[m][k]*Wp[m][t], Wp from global (L1/L2-hot)
//  4) out row staged in LDS (reuses buffer) -> 4 coalesced float4 stores
// 16 KB LDS/block, no __syncthreads -> high occupancy, full-line HBM writes.
__global__ __launch_bounds__(256) void k_main(
    const float* __restrict__ pos, const float* __restrict__ feat,
    const float4* __restrict__ Wp, const float* __restrict__ Wsc,
    const int* __restrict__ offs, const int* __restrict__ cnt,
    const int* __restrict__ csr_snd, float* __restrict__ out)
{
  __shared__ __align__(16) float smS[4][1024];   // 16 KB: SH stage / A / out

  const int tid = threadIdx.x, wv = tid>>6, lane = tid&63;
  const int ml = lane&31, hh = lane>>5;
  const int n = blockIdx.x*4 + wv;          // 12500*4 == 50000
  const float pnx=pos[n*3], pny=pos[n*3+1], pnz=pos[n*3+2];
  const int start = offs[n], deg = cnt[n];
  const int nch = (deg+63)>>6;

  float acc[8];
  #pragma unroll
  for (int j=0;j<8;++j) acc[j]=0.f;

  const float SC3=1.7320508f, SC5=2.236068f, SC7=2.6457513f, SC15=3.8729833f,
              SC42=6.4807407f, SC70=8.3666003f, SC105=10.246951f;

  // ---- phase 1: edge aggregation ----
  for (int c=0; c<nch; ++c){
    const int base = c<<6;
    int cn = deg - base; cn = (cn>64)?64:cn;     // >=1 inside loop
    int sE = 0;
    if (lane < cn){
      sE = csr_snd[start+base+lane];
      float rx = pnx - pos[sE*3];
      float ry = pny - pos[sE*3+1];
      float rz = pnz - pos[sE*3+2];
      float r = sqrtf(rx*rx+ry*ry+rz*rz);
      float inv = 1.0f/fmaxf(r,1e-12f);
      float x=rx*inv, y=ry*inv, z=rz*inv;
      float x2=x*x, y2=y*y, z2=z*z;
      float s1=SC3*x, s2=SC3*y, s3=SC3*z;
      float s4=SC15*x*y, s5=SC15*y*z, s6=0.5f*SC5*(3.f*z2-1.f), s7=SC15*x*z;
      float s8=0.5f*SC15*(x2-y2);
      float s9 =0.25f*SC70*y*(3.f*x2-y2);
      float s10=SC105*x*y*z;
      float s11=0.25f*SC42*y*(5.f*z2-1.f);
      float s12=0.5f*SC7*z*(5.f*z2-3.f);
      float s13=0.25f*SC42*x*(5.f*z2-1.f);
      float s14=0.5f*SC105*z*(x2-y2);
      float s15=0.25f*SC70*x*(x2-3.f*y2);
      float4* wp = (float4*)&smS[wv][lane*16];
      wp[0] = make_float4(1.0f,s1,s2,s3);
      wp[1] = make_float4(s4,s5,s6,s7);
      wp[2] = make_float4(s8,s9,s10,s11);
      wp[3] = make_float4(s12,s13,s14,s15);
    }
    // same-wave LDS producer->consumer ordering (waves independent)
    asm volatile("s_waitcnt lgkmcnt(0)" ::: "memory");
    #pragma unroll 8
    for (int it=0; it<cn; ++it){
      int s = __builtin_amdgcn_readlane(sE, it);   // uniform sender id
      float f = feat[(size_t)s*32 + ml];           // 128B segment, L2-hot
      const float4* rp = (const float4*)&smS[wv][it*16 + hh*8];
      float4 q0=rp[0], q1=rp[1];                   // broadcast reads
      acc[0]+=f*q0.x; acc[1]+=f*q0.y; acc[2]+=f*q0.z; acc[3]+=f*q0.w;
      acc[4]+=f*q1.x; acc[5]+=f*q1.y; acc[6]+=f*q1.z; acc[7]+=f*q1.w;
    }
    asm volatile("" ::: "memory");  // reads before next chunk's overwrites
  }

  // ---- phase 2: acc -> LDS A[m][16] (reuse smS) ----
  {
    float4* ap = (float4*)&smS[wv][ml*16 + hh*8];
    ap[0] = make_float4(acc[0],acc[1],acc[2],acc[3]);
    ap[1] = make_float4(acc[4],acc[5],acc[6],acc[7]);
  }
  asm volatile("s_waitcnt lgkmcnt(0)" ::: "memory");

  // ---- phase 3: per-node transform, W from global (L1-hot) ----
  float oa[16];
  #pragma unroll
  for (int k=0;k<16;++k) oa[k]=0.f;
  float osc = 0.f;
  const float4* f4 = (const float4*)(feat + (size_t)n*32);

  #pragma unroll 2
  for (int g=0; g<8; ++g){
    float4 fsv = f4[g];                           // wave-uniform, L1-hot
    #pragma unroll
    for (int mm=0; mm<4; ++mm){
      const int m = g*4+mm;
      float4 wq = Wp[m*64 + lane];                // 1KB coalesced, L1/L2
      float  w4 = Wsc[m*64 + lane];
      const float4* Ap = (const float4*)&smS[wv][m*16];   // broadcast
      float4 a0=Ap[0], a1=Ap[1], a2=Ap[2], a3=Ap[3];
      const float fsm = (mm==0)?fsv.x:(mm==1)?fsv.y:(mm==2)?fsv.z:fsv.w;
      oa[0] += a0.x*wq.x;
      oa[1] += a0.y*wq.y; oa[2] += a0.z*wq.y; oa[3] += a0.w*wq.y;
      oa[4] += a1.x*wq.z; oa[5] += a1.y*wq.z; oa[6] += a1.z*wq.z;
      oa[7] += a1.w*wq.z; oa[8] += a2.x*wq.z;
      oa[9] += a2.y*wq.w; oa[10]+= a2.z*wq.w; oa[11]+= a2.w*wq.w;
      oa[12]+= a3.x*wq.w; oa[13]+= a3.y*wq.w; oa[14]+= a3.z*wq.w; oa[15]+= a3.w*wq.w;
      osc += fsm*w4;
    }
  }
  asm volatile("" ::: "memory");   // A reads before out-stage overwrites

  // ---- phase 4: stage out row in LDS, then coalesced float4 stores ----
  const float S = 0.17677669529663687f;   // 1/sqrt(32)
  const float S8 = S*0.125f;              // edge terms also carry /DENOM
  float* ol = &smS[wv][0];
  ol[lane] = oa[0]*S8 + osc*S;
  #pragma unroll
  for (int i=0;i<3;++i) ol[64  + lane*3 + i] = oa[1+i]*S8;
  #pragma unroll
  for (int i=0;i<5;++i) ol[256 + lane*5 + i] = oa[4+i]*S8;
  #pragma unroll
  for (int i=0;i<7;++i) ol[576 + lane*7 + i] = oa[9+i]*S8;
  asm volatile("s_waitcnt lgkmcnt(0)" ::: "memory");

  float4* o4 = (float4*)(out + (size_t)n*1024);
  const float4* s4 = (const float4*)&smS[wv][0];
  #pragma unroll
  for (int i=0;i<4;++i) o4[i*64 + lane] = s4[i*64 + lane];
}

extern "C" void kernel_launch(void* const* d_in, const int* in_sizes, int n_in,
                              void* d_out, int out_size, void* d_ws, size_t ws_size,
                              hipStream_t stream) {
  const float* pos  = (const float*)d_in[0];
  const float* feat = (const float*)d_in[1];
  const float* W0   = (const float*)d_in[2];
  const float* W1   = (const float*)d_in[3];
  const float* W2   = (const float*)d_in[4];
  const float* W3   = (const float*)d_in[5];
  const float* Wsc  = (const float*)d_in[6];
  const int*  snd   = (const int*)d_in[7];
  const int*  rcv   = (const int*)d_in[8];
  float* out = (float*)d_out;

  int* ws      = (int*)d_ws;
  int* cnt     = ws;            // 50000
  int* offs    = ws + 50000;    // 50000
  int* cursor  = ws + 100000;   // 50000
  int* bsum    = ws + 150000;   // 256
  int* csr_snd = ws + 150272;   // 400000  (ints end at 550272; 16B aligned)
  float4* Wp   = (float4*)(ws + 550272);          // 2048 float4 = 32 KB

  hipMemsetAsync(cnt, 0, NN*sizeof(int), stream);
  k_hist   <<<(NE+255)/256, 256, 0, stream>>>(rcv, cnt);
  k_scanA  <<<SCAN_NB, 256, 0, stream>>>(cnt, bsum);
  k_scanB  <<<1, 256, 0, stream>>>(bsum);
  k_scanC  <<<SCAN_NB, 256, 0, stream>>>(cnt, bsum, offs, cursor);
  k_scatter<<<(NE+255)/256, 256, 0, stream>>>(rcv, snd, cursor, csr_snd);
  k_prepW  <<<8, 256, 0, stream>>>(W0, W1, W2, W3, Wp);
  k_main   <<<12500, 256, 0, stream>>>(pos, feat, Wp, Wsc,
                                       offs, cnt, csr_snd, out);
}